// Round 2
// baseline (34.405 us; speedup 1.0000x reference)
//
#include <hip/hip_runtime.h>

#define N_CLASSES 512
#define EPS_F 1e-7f
#define BLOCK 256
#define SPT 4  // samples per thread

// Fused kernel: per-sample NLL -> per-block LDS class histogram -> global
// atomic flush -> last block computes mean-of-class-means and writes scalar.
__global__ __launch_bounds__(BLOCK) void nll_fused_kernel(
    const float* __restrict__ close_er,
    const int*   __restrict__ y,
    const float* __restrict__ max_dis,
    const float* __restrict__ margin_p,
    float* __restrict__ g_sums,
    float* __restrict__ g_counts,
    int*   __restrict__ g_ticket,
    float* __restrict__ out,
    int n)
{
    __shared__ float        s_md[N_CLASSES];
    __shared__ float        s_sum[N_CLASSES];
    __shared__ unsigned int s_cnt[N_CLASSES];
    __shared__ float        s_red[8];
    __shared__ bool         s_last;

    const int tid = threadIdx.x;
    const float margin = margin_p[0];

    for (int c = tid; c < N_CLASSES; c += BLOCK) {
        s_md[c]  = max_dis[c];
        s_sum[c] = 0.0f;
        s_cnt[c] = 0u;
    }
    __syncthreads();

    // ---- phase 1: gather + NLL + LDS histogram (4 samples/thread) ----
    const int base = (blockIdx.x * BLOCK + tid) * SPT;
    if (base + SPT <= n) {
        const int4 y4 = *reinterpret_cast<const int4*>(&y[base]);
        const int c0 = y4.x, c1 = y4.y, c2 = y4.z, c3 = y4.w;
        // issue all 4 gathers before any use -> 4 outstanding loads
        const float ce0 = close_er[(size_t)(base + 0) * N_CLASSES + c0];
        const float ce1 = close_er[(size_t)(base + 1) * N_CLASSES + c1];
        const float ce2 = close_er[(size_t)(base + 2) * N_CLASSES + c2];
        const float ce3 = close_er[(size_t)(base + 3) * N_CLASSES + c3];
        const float x0 = ce0 - s_md[c0] - margin;
        const float x1 = ce1 - s_md[c1] - margin;
        const float x2 = ce2 - s_md[c2] - margin;
        const float x3 = ce3 - s_md[c3] - margin;
        float s0 = 1.0f / (1.0f + __expf(-x0));
        float s1 = 1.0f / (1.0f + __expf(-x1));
        float s2 = 1.0f / (1.0f + __expf(-x2));
        float s3 = 1.0f / (1.0f + __expf(-x3));
        s0 = fminf(fmaxf(s0, EPS_F), 1.0f - EPS_F);
        s1 = fminf(fmaxf(s1, EPS_F), 1.0f - EPS_F);
        s2 = fminf(fmaxf(s2, EPS_F), 1.0f - EPS_F);
        s3 = fminf(fmaxf(s3, EPS_F), 1.0f - EPS_F);
        atomicAdd(&s_sum[c0], -__logf(s0));
        atomicAdd(&s_sum[c1], -__logf(s1));
        atomicAdd(&s_sum[c2], -__logf(s2));
        atomicAdd(&s_sum[c3], -__logf(s3));
        atomicAdd(&s_cnt[c0], 1u);
        atomicAdd(&s_cnt[c1], 1u);
        atomicAdd(&s_cnt[c2], 1u);
        atomicAdd(&s_cnt[c3], 1u);
    } else {
        for (int k = 0; k < SPT; ++k) {
            const int i = base + k;
            if (i < n) {
                const int c = y[i];
                const float ce = close_er[(size_t)i * N_CLASSES + c];
                const float x  = ce - s_md[c] - margin;
                float s = 1.0f / (1.0f + __expf(-x));
                s = fminf(fmaxf(s, EPS_F), 1.0f - EPS_F);
                atomicAdd(&s_sum[c], -__logf(s));
                atomicAdd(&s_cnt[c], 1u);
            }
        }
    }
    __syncthreads();

    // ---- phase 2: flush per-block partials to global ----
    for (int c = tid; c < N_CLASSES; c += BLOCK) {
        const unsigned int cnt = s_cnt[c];
        if (cnt != 0u) {
            atomicAdd(&g_sums[c],   s_sum[c]);
            atomicAdd(&g_counts[c], (float)cnt);  // exact: counts < 2^24
        }
    }

    // ---- phase 3: last block finalizes ----
    __threadfence();
    if (tid == 0) {
        const int t = atomicAdd(g_ticket, 1);
        s_last = (t == (int)gridDim.x - 1);
    }
    __syncthreads();
    if (!s_last) return;
    __threadfence();  // acquire: see all blocks' flushes

    float m = 0.0f, j = 0.0f;
    for (int c = tid; c < N_CLASSES; c += BLOCK) {
        const float cnt = g_counts[c];
        if (cnt > 0.0f) {
            m += g_sums[c] / cnt;
            j += 1.0f;
        }
    }
    // wave reduce (64 lanes), then across the 4 waves via LDS
    for (int off = 32; off > 0; off >>= 1) {
        m += __shfl_down(m, off);
        j += __shfl_down(j, off);
    }
    const int wave = tid >> 6;
    if ((tid & 63) == 0) {
        s_red[wave * 2]     = m;
        s_red[wave * 2 + 1] = j;
    }
    __syncthreads();
    if (tid == 0) {
        float M = 0.0f, J = 0.0f;
        for (int w = 0; w < BLOCK / 64; ++w) {
            M += s_red[w * 2];
            J += s_red[w * 2 + 1];
        }
        out[0] = M / J;
    }
}

extern "C" void kernel_launch(void* const* d_in, const int* in_sizes, int n_in,
                              void* d_out, int out_size, void* d_ws, size_t ws_size,
                              hipStream_t stream) {
    const float* close_er = (const float*)d_in[0];
    const int*   y        = (const int*)d_in[1];
    const float* max_dis  = (const float*)d_in[2];
    const float* margin   = (const float*)d_in[3];
    float* out = (float*)d_out;

    const int n = in_sizes[1];  // N samples

    float* g_sums   = (float*)d_ws;
    float* g_counts = g_sums + N_CLASSES;
    int*   g_ticket = (int*)(g_counts + N_CLASSES);

    // ws is poisoned once (0xAA) and never re-poisoned between replays:
    // zero accumulators + ticket every call (deterministic).
    hipMemsetAsync(d_ws, 0, (2 * N_CLASSES + 1) * sizeof(float), stream);

    const int grid = (n + BLOCK * SPT - 1) / (BLOCK * SPT);  // 256 at N=262144
    nll_fused_kernel<<<grid, BLOCK, 0, stream>>>(close_er, y, max_dis, margin,
                                                 g_sums, g_counts, g_ticket,
                                                 out, n);
}